// Round 6
// baseline (203.648 us; speedup 1.0000x reference)
//
#include <hip/hip_runtime.h>
#include <hip/hip_bf16.h>

#define NTOK 4096
#define DIM  1024
#define NEXP 8
#define HID  2048
#define HROWS 8448   // capacity rows for h (8192 expected + slack)

typedef __attribute__((ext_vector_type(8))) __bf16 bf16x8;
typedef __attribute__((ext_vector_type(4))) float  f32x4;
typedef __attribute__((address_space(1))) const unsigned char gconst_u8;
typedef __attribute__((address_space(3))) unsigned char lds_u8;

__device__ __forceinline__ unsigned short f2bf(float f) {
    unsigned u = __float_as_uint(f);
    u += 0x7fffu + ((u >> 16) & 1u);   // RNE
    return (unsigned short)(u >> 16);
}

__device__ __forceinline__ void gload16(const void* g, void* l) {
    __builtin_amdgcn_global_load_lds((gconst_u8*)g, (lds_u8*)l, 16, 0, 0);
}

#define WAITK(N) asm volatile("s_waitcnt vmcnt(" #N ") lgkmcnt(0)" ::: "memory")
#define BAR() do { __builtin_amdgcn_s_barrier(); __builtin_amdgcn_sched_barrier(0); } while (0)

// ---------------- prep: W1 convert + x convert + build_lists ----------------
// bid 0..2047    : W1 -> W1F fragment-tiled bf16
// bid 2048..4095 : x -> xbf
// bid 4096..4111 : build per-expert token lists
// W1F elem((e*32+ks)*128 + f, l, j) = W1[e][k = ks*32+(l>>4)*8+j][c = f*16+(l&15)]
__global__ __launch_bounds__(256) void prep(
    const float* __restrict__ x, const float* __restrict__ routing,
    const float* __restrict__ W1,
    unsigned short* __restrict__ xbf, unsigned short* __restrict__ W1F,
    int* __restrict__ counts, int* __restrict__ lists,
    int* __restrict__ slotrec, int* __restrict__ scnt)
{
    const int bid = blockIdx.x;
    const int t = threadIdx.x;
    if (bid >= 4096) {            // build_lists
        int n = (bid - 4096) * 256 + t;
        if (n >= NTOK) return;
        int sc = 0;
        #pragma unroll
        for (int e = 0; e < NEXP; ++e) {
            if (routing[n * NEXP + e] > 0.0f) {
                int i = atomicAdd(&counts[e], 1);
                if (i < NTOK) {
                    lists[e * NTOK + i] = n;
                    if (sc < 4) slotrec[n * 4 + sc] = (e << 20) | i;
                    ++sc;
                }
            }
        }
        scnt[n] = sc;
        return;
    }
    if (bid >= 2048) {            // convert x
        int i = ((bid - 2048) * 256 + t) * 8;
        float4 a = *(const float4*)(x + i);
        float4 b = *(const float4*)(x + i + 4);
        unsigned short v[8];
        v[0] = f2bf(a.x); v[1] = f2bf(a.y); v[2] = f2bf(a.z); v[3] = f2bf(a.w);
        v[4] = f2bf(b.x); v[5] = f2bf(b.y); v[6] = f2bf(b.z); v[7] = f2bf(b.w);
        *(uint4*)(xbf + i) = *(const uint4*)v;
        return;
    }
    // W1: e(8) x ks(32) x fblk(8), 256 cols x 32 k per block
    int e = bid >> 8, ks = (bid >> 3) & 31, fblk = bid & 7;
    const float* src = W1 + ((size_t)e * DIM + ks * 32) * HID + fblk * 256;
    unsigned short* dst = W1F + (((size_t)(e * 32 + ks) * 128) + fblk * 16) * 512;
    // stride 266 shorts: 8 rows -> bank offset 8; the 4 sixteen-lane transpose groups
    // hit bank sets {0..7},{8..15},{16..23},{24..31} -> conflict-free reads
    __shared__ unsigned short lds[32][266];
    const int kr = t >> 3, ch = t & 7;
    #pragma unroll
    for (int q = 0; q < 8; ++q) {
        float4 f4 = *(const float4*)(src + (size_t)kr * HID + ch * 32 + q * 4);
        int c = ch * 32 + q * 4;
        lds[kr][c + 0] = f2bf(f4.x); lds[kr][c + 1] = f2bf(f4.y);
        lds[kr][c + 2] = f2bf(f4.z); lds[kr][c + 3] = f2bf(f4.w);
    }
    __syncthreads();
    uint4* dv = (uint4*)dst;
    #pragma unroll
    for (int i = 0; i < 4; ++i) {
        int Q = t + 256 * i;
        int fl = Q >> 6, l = Q & 63;
        int cb = fl * 16 + (l & 15), rb = (l >> 4) * 8;
        unsigned short v[8];
        #pragma unroll
        for (int j = 0; j < 8; ++j) v[j] = lds[rb + j][cb];
        dv[Q] = *(const uint4*)v;
    }
}

// ---------------- GEMM1 (+appended W2 convert): ----------------
// gemm1: BM=256 BN=128 BK=32, 512 thr (8 waves 4Mx2N, 64x64/wave)
//   m97 discipline: 2-buffer (48KB), STAGE-first, vmcnt(0)+barrier at step end
//   -> 3 blocks/CU (24 waves) vs the old 3-buf 72KB 2 blocks/CU
//   grid ids 0..767: id = ((nt*6 + mt) << 3) | e
// bids 768..1791: W2 -> W2F fragment-tiled convert (1024 units) -- proven placement
// W2F elem((e*64+ks)*64 + f, l, j) = W2[e][k=ks*32+(l>>4)*8+j][c=f*16+(l&15)]
__global__ __launch_bounds__(512, 4) void gemm1_gelu(
    const unsigned short* __restrict__ xbf, const unsigned short* __restrict__ W1F,
    const float* __restrict__ b1, const int* __restrict__ counts,
    const int* __restrict__ lists, unsigned short* __restrict__ h,
    const float* __restrict__ W2, unsigned short* __restrict__ W2F)
{
    __shared__ uint4 SM[3072];   // 48KB: 2 x (A 1024 + B 512) uint4; epilogue uses 36KB
    const int bid = blockIdx.x;
    const int t = threadIdx.x;

    if (bid >= 768) {            // ---- W2 -> W2F convert (512 thr) ----
        const int unit = bid - 768;
        const int e = unit & 7, ks = (unit >> 3) & 63, half = unit >> 9;
        const float* src = W2 + ((size_t)e * HID + ks * 32) * DIM + half * 512;
        unsigned short* lds = (unsigned short*)SM;   // [32][522] = 33.4KB; conflict-free stride
        const int kr = t >> 4, ch = t & 15;
        #pragma unroll
        for (int q = 0; q < 8; ++q) {
            float4 f4 = *(const float4*)(src + (size_t)kr * DIM + ch * 32 + q * 4);
            int c = ch * 32 + q * 4;
            lds[kr * 522 + c + 0] = f2bf(f4.x); lds[kr * 522 + c + 1] = f2bf(f4.y);
            lds[kr * 522 + c + 2] = f2bf(f4.z); lds[kr * 522 + c + 3] = f2bf(f4.w);
        }
        __syncthreads();
        uint4* dv = (uint4*)(W2F + (((size_t)(e * 64 + ks)) * 64 + half * 32) * 512);
        #pragma unroll
        for (int i = 0; i < 4; ++i) {
            int Q = t + 512 * i;
            int fl = Q >> 6, l = Q & 63;
            int cb = fl * 16 + (l & 15), rb = (l >> 4) * 8;
            unsigned short v[8];
            #pragma unroll
            for (int j = 0; j < 8; ++j) v[j] = lds[(rb + j) * 522 + cb];
            dv[Q] = *(const uint4*)v;
        }
        return;
    }

    // ---- gemm1 ----
    const int e  = bid & 7;
    const int q  = bid >> 3;       // 0..95
    const int mt = q % 6;          // 0..5
    const int nt = q / 6;          // 0..15

    int cnt = counts[e];
    int off = 0;
    #pragma unroll
    for (int j = 0; j < NEXP; ++j) if (j < e) off += counts[j];
    if (off + cnt > HROWS) cnt = HROWS - off;
    const int m0 = mt * 256;
    if (m0 >= cnt) return;

    const int lane = t & 63;
    const int wid  = t >> 6;     // 0..7
    const int wm   = wid >> 1;   // 0..3
    const int wn   = wid & 1;    // 0..1

    // A gather: wave w stages m-frags w and w+8 (rows f*16+(lane&15))
    const int gi0 = m0 + wid * 16 + (lane & 15);
    const int gi1 = gi0 + 128;
    const int tok0 = lists[e * NTOK + ((gi0 < cnt) ? gi0 : 0)];
    const int tok1 = lists[e * NTOK + ((gi1 < cnt) ? gi1 : 0)];
    const unsigned short* ag0 = xbf + (size_t)tok0 * DIM + (lane >> 4) * 8;
    const unsigned short* ag1 = xbf + (size_t)tok1 * DIM + (lane >> 4) * 8;

    // B: wave w stages col-frag nt*8+w
    const unsigned short* bg = W1F + ((size_t)(e * 32) * 128 + nt * 8 + wid) * 512 + lane * 8;

    f32x4 acc[4][4];
    #pragma unroll
    for (int m = 0; m < 4; ++m)
        #pragma unroll
        for (int n = 0; n < 4; ++n) acc[m][n] = (f32x4){0.f, 0.f, 0.f, 0.f};

#define STG1(P, KS) do { \
        gload16(ag0 + (KS) * 32, (P) + wid * 64); \
        gload16(ag1 + (KS) * 32, (P) + (wid + 8) * 64); \
        gload16(bg + (size_t)(KS) * 65536, (P) + 1024 + wid * 64); \
    } while (0)
#define CMP1(P) do { \
        const bf16x8* Af = (const bf16x8*)(P); \
        const bf16x8* Bf = (const bf16x8*)((P) + 1024); \
        bf16x8 af[4], bfr[4]; \
        _Pragma("unroll") for (int m = 0; m < 4; ++m) af[m] = Af[((wm * 4 + m) << 6) | lane]; \
        _Pragma("unroll") for (int n = 0; n < 4; ++n) bfr[n] = Bf[((wn * 4 + n) << 6) | lane]; \
        __builtin_amdgcn_s_setprio(1); \
        _Pragma("unroll") for (int m = 0; m < 4; ++m) \
            _Pragma("unroll") for (int n = 0; n < 4; ++n) \
                acc[m][n] = __builtin_amdgcn_mfma_f32_16x16x32_bf16(af[m], bfr[n], acc[m][n], 0, 0, 0); \
        __builtin_amdgcn_s_setprio(0); \
    } while (0)

    // m97 2-buffer schedule: STAGE(next) first (loads fly under compute),
    // compute current, then vmcnt(0)+barrier once per step.
    uint4 *Pc = SM, *Pn = SM + 1536;
    STG1(Pc, 0);
    WAITK(0); BAR();
    for (int T = 0; T < 31; ++T) {
        STG1(Pn, T + 1);          // issue next tile's loads
        CMP1(Pc);                 // ds_read + MFMA current tile (covers load latency)
        WAITK(0);                 // next tile landed
        BAR();
        uint4* tmp = Pc; Pc = Pn; Pn = tmp;
    }
    CMP1(Pc);                     // tile 31 (already staged + drained)
#undef STG1
#undef CMP1

    // ---- epilogue: bias + gelu -> XOR-swizzled LDS repack -> coalesced flush ----
    // Two 128-row passes of 36KB (fits the 48KB loop budget -> keeps 3 blocks/CU).
    asm volatile("s_waitcnt lgkmcnt(0)" ::: "memory");
    BAR();                                    // SM free to reuse
    unsigned short* hb = (unsigned short*)SM; // [128][144] shorts = 36KB
    const int lg = lane >> 4;                 // bank-octet group
    #pragma unroll
    for (int pass = 0; pass < 2; ++pass) {
        if ((wm >> 1) == pass) {              // waves wm={0,1} -> rows 0..127; wm={2,3} -> 128..255
            #pragma unroll
            for (int n = 0; n < 4; ++n) {
                const int cl = (wn * 4 + n) * 16 + (lane & 15);
                const float bb = b1[e * HID + nt * 128 + cl];
                #pragma unroll
                for (int m = 0; m < 4; ++m) {
                    const int il = (wm & 1) * 64 + m * 16 + (lg << 2);  // local row in pass
                    const int scl = cl ^ (lg << 4);   // swizzle: group -> distinct 32B block
                    #pragma unroll
                    for (int r = 0; r < 4; ++r) {
                        float v = acc[m][n][r] + bb;
                        float g = 0.5f * v * (1.0f + erff(v * 0.70710678118654752f));
                        hb[(il + r) * 144 + scl] = f2bf(g);
                    }
                }
            }
        }
        __syncthreads();
        #pragma unroll
        for (int s = 0; s < 4; ++s) {
            const int row = s * 32 + (t >> 4);          // 0..127 local
            const int grow = m0 + pass * 128 + row;
            if (grow < cnt) {
                const int p = t & 15;
                const int gblk = ((p >> 1) ^ ((row >> 2) & 3));    // un-swizzle 32B block
                const int gc = gblk * 16 + (p & 1) * 8;
                uint4 v = *(const uint4*)(hb + row * 144 + p * 8);
                *(uint4*)(h + (size_t)(off + grow) * HID + nt * 128 + gc) = v;
            }
        }
        __syncthreads();
    }
}

// ---------------- GEMM2: cbuf[slot] = wt * (h @ W2F + b2[e]) ----------------
// BM=128 BN=128 BK=32, 256 thr (4 waves 2Mx2N, 64x64/wave)
// m97 discipline: 2-buffer (32KB) -> 4-5 blocks/CU
// grid: id = ((mt*8 + nt) << 3) | e
__global__ __launch_bounds__(256, 4) void gemm2_store(
    const unsigned short* __restrict__ h, const unsigned short* __restrict__ W2F,
    const float* __restrict__ b2, const int* __restrict__ counts,
    const int* __restrict__ lists, const float* __restrict__ routing,
    float* __restrict__ cbuf)
{
    const int id = blockIdx.x;
    const int e  = id & 7;
    const int nt = (id >> 3) & 7;
    const int mt = id >> 6;          // 0..11

    int cnt = counts[e];
    int off = 0;
    #pragma unroll
    for (int j = 0; j < NEXP; ++j) if (j < e) off += counts[j];
    if (off + cnt > HROWS) cnt = HROWS - off;
    const int m0 = mt * 128;
    if (m0 >= cnt) return;

    __shared__ uint4 SM[2048];   // 2 x (A 512 + B 512) uint4 = 32KB

    const int t    = threadIdx.x;
    const int lane = t & 63;
    const int wid  = t >> 6;     // 0..3
    const int wm   = wid >> 1;   // 0..1
    const int wn   = wid & 1;    // 0..1

    // A: wave w stages m-frags w and w+4 (h rows compact per expert)
    const int r0 = off + m0 + wid * 16 + (lane & 15);
    const unsigned short* ag0 = h + (size_t)r0 * HID + (lane >> 4) * 8;
    const unsigned short* ag1 = ag0 + (size_t)64 * HID;

    // B: wave w stages col-frags nt*8+w and nt*8+w+4
    const unsigned short* bg0 = W2F + ((size_t)(e * 64) * 64 + nt * 8 + wid) * 512 + lane * 8;
    const unsigned short* bg1 = bg0 + 4 * 512;

    f32x4 acc[4][4];
    #pragma unroll
    for (int m = 0; m < 4; ++m)
        #pragma unroll
        for (int n = 0; n < 4; ++n) acc[m][n] = (f32x4){0.f, 0.f, 0.f, 0.f};

#define STG2(P, KS) do { \
        gload16(ag0 + (KS) * 32, (P) + wid * 64); \
        gload16(ag1 + (KS) * 32, (P) + (wid + 4) * 64); \
        gload16(bg0 + (size_t)(KS) * 32768, (P) + 512 + wid * 64); \
        gload16(bg1 + (size_t)(KS) * 32768, (P) + 512 + (wid + 4) * 64); \
    } while (0)
#define CMP2(P) do { \
        const bf16x8* Af = (const bf16x8*)(P); \
        const bf16x8* Bf = (const bf16x8*)((P) + 512); \
        bf16x8 af[4], bfr[4]; \
        _Pragma("unroll") for (int m = 0; m < 4; ++m) af[m] = Af[((wm * 4 + m) << 6) | lane]; \
        _Pragma("unroll") for (int n = 0; n < 4; ++n) bfr[n] = Bf[((wn * 4 + n) << 6) | lane]; \
        __builtin_amdgcn_s_setprio(1); \
        _Pragma("unroll") for (int m = 0; m < 4; ++m) \
            _Pragma("unroll") for (int n = 0; n < 4; ++n) \
                acc[m][n] = __builtin_amdgcn_mfma_f32_16x16x32_bf16(af[m], bfr[n], acc[m][n], 0, 0, 0); \
        __builtin_amdgcn_s_setprio(0); \
    } while (0)

    uint4 *Pc = SM, *Pn = SM + 1024;
    STG2(Pc, 0);
    WAITK(0); BAR();
    for (int T = 0; T < 63; ++T) {
        STG2(Pn, T + 1);
        CMP2(Pc);
        WAITK(0);
        BAR();
        uint4* tmp = Pc; Pc = Pn; Pn = tmp;
    }
    CMP2(Pc);
#undef STG2
#undef CMP2

    const int n0 = nt * 128;
    int cols[4]; float bb[4];
    #pragma unroll
    for (int n = 0; n < 4; ++n) {
        cols[n] = n0 + (wn * 4 + n) * 16 + (lane & 15);
        bb[n] = b2[e * DIM + cols[n]];
    }
    #pragma unroll
    for (int m = 0; m < 4; ++m) {
        const int ib = m0 + (wm * 4 + m) * 16 + ((lane >> 4) << 2);
        #pragma unroll
        for (int r = 0; r < 4; ++r) {
            const int i = ib + r;
            if (i < cnt) {
                const int token = lists[e * NTOK + i];
                const float wt = routing[token * NEXP + e];
                float* dst = cbuf + (size_t)(off + i) * DIM;
                #pragma unroll
                for (int n = 0; n < 4; ++n)
                    dst[cols[n]] = wt * (acc[m][n][r] + bb[n]);
            }
        }
    }
}

// ---------------- combine: out[n] = sum over the token's slots ----------------
__global__ __launch_bounds__(256) void combine(
    const float* __restrict__ cbuf, const int* __restrict__ counts,
    const int* __restrict__ slotrec, const int* __restrict__ scnt,
    float* __restrict__ out)
{
    const int n = blockIdx.x;
    const int t = threadIdx.x;
    int offs[NEXP];
    int s = 0;
    #pragma unroll
    for (int e = 0; e < NEXP; ++e) { offs[e] = s; s += counts[e]; }
    int sc = scnt[n]; if (sc > 4) sc = 4;
    float4 acc = {0.f, 0.f, 0.f, 0.f};
    for (int j = 0; j < sc; ++j) {
        int rec = slotrec[n * 4 + j];
        int e = rec >> 20, i = rec & 0xFFFFF;
        float4 v = ((const float4*)(cbuf + (size_t)(offs[e] + i) * DIM))[t];
        acc.x += v.x; acc.y += v.y; acc.z += v.z; acc.w += v.w;
    }
    ((float4*)(out + (size_t)n * DIM))[t] = acc;
}

extern "C" void kernel_launch(void* const* d_in, const int* in_sizes, int n_in,
                              void* d_out, int out_size, void* d_ws, size_t ws_size,
                              hipStream_t stream) {
    const float* x       = (const float*)d_in[0];
    const float* routing = (const float*)d_in[1];
    const float* W1      = (const float*)d_in[2];
    const float* b1      = (const float*)d_in[3];
    const float* W2      = (const float*)d_in[4];
    const float* b2      = (const float*)d_in[5];
    float* out = (float*)d_out;

    char* ws = (char*)d_ws;
    int* counts          = (int*)ws;                            // 256 B
    int* lists           = (int*)(ws + 0x400);                  // 128 KB
    int* slotrec         = (int*)(ws + 0x20400);                // 64 KB
    int* scnt            = (int*)(ws + 0x30400);                // 16 KB
    unsigned short* xbf  = (unsigned short*)(ws + 0x40000);     // 8 MB
    float*          cbuf = (float*)(ws + 0x40000);              // overlays xbf+W1F (dead after gemm1)
    unsigned short* W1F  = (unsigned short*)(ws + 0x840000);    // 32 MB
    unsigned short* W2F  = (unsigned short*)(ws + 0x2840000);   // 32 MB
    unsigned short* h    = (unsigned short*)(ws + 0x4840000);   // 35 MB

    hipMemsetAsync(counts, 0, 256, stream);
    prep<<<4112, 256, 0, stream>>>(x, routing, W1, xbf, W1F,
                                   counts, lists, slotrec, scnt);
    gemm1_gelu<<<1792, 512, 0, stream>>>(xbf, W1F, b1, counts, lists, h, W2, W2F);
    gemm2_store<<<768, 256, 0, stream>>>(h, W2F, b2, counts, lists, routing, cbuf);
    combine<<<NTOK, 256, 0, stream>>>(cbuf, counts, slotrec, scnt, out);
}

// Round 7
// 202.780 us; speedup vs baseline: 1.0043x; 1.0043x over previous
//
#include <hip/hip_runtime.h>
#include <hip/hip_bf16.h>

#define NTOK 4096
#define DIM  1024
#define NEXP 8
#define HID  2048
#define HROWS 8448   // capacity rows for compact (expert,token) slots (8192 expected + slack)

typedef __attribute__((ext_vector_type(8))) __bf16 bf16x8;
typedef __attribute__((ext_vector_type(4))) float  f32x4;
typedef __attribute__((address_space(1))) const unsigned char gconst_u8;
typedef __attribute__((address_space(3))) unsigned char lds_u8;

__device__ __forceinline__ unsigned short f2bf(float f) {
    unsigned u = __float_as_uint(f);
    u += 0x7fffu + ((u >> 16) & 1u);   // RNE
    return (unsigned short)(u >> 16);
}

__device__ __forceinline__ void gload16(const void* g, void* l) {
    __builtin_amdgcn_global_load_lds((gconst_u8*)g, (lds_u8*)l, 16, 0, 0);
}

#define WAITK(N) asm volatile("s_waitcnt vmcnt(" #N ") lgkmcnt(0)" ::: "memory")
#define BAR() do { __builtin_amdgcn_s_barrier(); __builtin_amdgcn_sched_barrier(0); } while (0)

// ---------------- prep: W1 convert + build_lists ----------------
// bid 0..2047 : W1 -> W1F fragment-tiled bf16
// bid 2048..  : build per-expert token lists
// W1F elem((e*32+ks)*128 + f, l, j) = W1[e][k = ks*32+(l>>4)*8+j][c = f*16+(l&15)]
__global__ __launch_bounds__(256) void prep(
    const float* __restrict__ x, const float* __restrict__ routing,
    const float* __restrict__ W1,
    unsigned short* __restrict__ W1F,
    int* __restrict__ counts, int* __restrict__ lists,
    int* __restrict__ slotrec, int* __restrict__ scnt)
{
    const int bid = blockIdx.x;
    const int t = threadIdx.x;
    if (bid >= 2048) {            // build_lists
        int n = (bid - 2048) * 256 + t;
        if (n >= NTOK) return;
        int sc = 0;
        #pragma unroll
        for (int e = 0; e < NEXP; ++e) {
            if (routing[n * NEXP + e] > 0.0f) {
                int i = atomicAdd(&counts[e], 1);
                if (i < NTOK) {
                    lists[e * NTOK + i] = n;
                    if (sc < 4) slotrec[n * 4 + sc] = (e << 20) | i;
                    ++sc;
                }
            }
        }
        scnt[n] = sc;
        return;
    }
    // W1: e(8) x ks(32) x fblk(8), 256 cols x 32 k per block
    int e = bid >> 8, ks = (bid >> 3) & 31, fblk = bid & 7;
    const float* src = W1 + ((size_t)e * DIM + ks * 32) * HID + fblk * 256;
    unsigned short* dst = W1F + (((size_t)(e * 32 + ks) * 128) + fblk * 16) * 512;
    // stride 266 shorts: 8 rows -> bank offset 8; the 4 sixteen-lane transpose groups
    // hit bank sets {0..7},{8..15},{16..23},{24..31} -> conflict-free reads
    __shared__ unsigned short lds[32][266];
    const int kr = t >> 3, ch = t & 7;
    #pragma unroll
    for (int q = 0; q < 8; ++q) {
        float4 f4 = *(const float4*)(src + (size_t)kr * HID + ch * 32 + q * 4);
        int c = ch * 32 + q * 4;
        lds[kr][c + 0] = f2bf(f4.x); lds[kr][c + 1] = f2bf(f4.y);
        lds[kr][c + 2] = f2bf(f4.z); lds[kr][c + 3] = f2bf(f4.w);
    }
    __syncthreads();
    uint4* dv = (uint4*)dst;
    #pragma unroll
    for (int i = 0; i < 4; ++i) {
        int Q = t + 256 * i;
        int fl = Q >> 6, l = Q & 63;
        int cb = fl * 16 + (l & 15), rb = (l >> 4) * 8;
        unsigned short v[8];
        #pragma unroll
        for (int j = 0; j < 8; ++j) v[j] = lds[rb + j][cb];
        dv[Q] = *(const uint4*)v;
    }
}

// ---------------- gather_x: xg[row] = bf16(x[lists[e][row-off_e]]) ----------------
// Materializes the expert-compact activation matrix so gemm1's A operand streams
// contiguous rows (same access pattern as gemm2's A from h) instead of randomly
// gathering 2KB token rows every K-step.
// 16 rows/block, 16 threads/row, 64 cols/thread.
__global__ __launch_bounds__(256) void gather_x(
    const float* __restrict__ x, const int* __restrict__ counts,
    const int* __restrict__ lists, unsigned short* __restrict__ xg)
{
    const int t = threadIdx.x;
    const int row = blockIdx.x * 16 + (t >> 4);
    int offs[NEXP + 1];
    offs[0] = 0;
    #pragma unroll
    for (int e = 0; e < NEXP; ++e) offs[e + 1] = offs[e] + counts[e];
    int total = offs[NEXP]; if (total > HROWS) total = HROWS;
    if (row >= total) return;
    int e = 0;
    #pragma unroll
    for (int j = 1; j < NEXP; ++j) if (row >= offs[j]) e = j;
    const int token = lists[e * NTOK + (row - offs[e])];
    const int c0 = (t & 15) * 64;
    const float* src = x + (size_t)token * DIM + c0;
    unsigned short* dst = xg + (size_t)row * DIM + c0;
    #pragma unroll
    for (int q = 0; q < 8; ++q) {
        float4 a = *(const float4*)(src + q * 8);
        float4 b = *(const float4*)(src + q * 8 + 4);
        unsigned short v[8];
        v[0] = f2bf(a.x); v[1] = f2bf(a.y); v[2] = f2bf(a.z); v[3] = f2bf(a.w);
        v[4] = f2bf(b.x); v[5] = f2bf(b.y); v[6] = f2bf(b.z); v[7] = f2bf(b.w);
        *(uint4*)(dst + q * 8) = *(const uint4*)v;
    }
}

// ---------------- GEMM1 (+appended W2 convert): ----------------
// gemm1: BM=256 BN=128 BK=32, 512 thr (8 waves 4Mx2N, 64x64/wave)
//   3-buffer depth-2 prefetch, 1 barrier/step, vmcnt(3) -- the verified discipline
//   A now streams CONTIGUOUS rows from xg (expert-compact), like gemm2's A from h.
//   grid ids 0..767: id = ((nt*6 + mt) << 3) | e
// bids 768..1791: W2 -> W2F fragment-tiled convert (1024 units) -- proven placement
// W2F elem((e*64+ks)*64 + f, l, j) = W2[e][k=ks*32+(l>>4)*8+j][c=f*16+(l&15)]
__global__ __launch_bounds__(512, 4) void gemm1_gelu(
    const unsigned short* __restrict__ xg, const unsigned short* __restrict__ W1F,
    const float* __restrict__ b1, const int* __restrict__ counts,
    unsigned short* __restrict__ h,
    const float* __restrict__ W2, unsigned short* __restrict__ W2F)
{
    __shared__ uint4 SM[4608];   // 3 x (A 1024 + B 512) uint4 = 72KB
    const int bid = blockIdx.x;
    const int t = threadIdx.x;

    if (bid >= 768) {            // ---- W2 -> W2F convert (512 thr) ----
        const int unit = bid - 768;
        const int e = unit & 7, ks = (unit >> 3) & 63, half = unit >> 9;
        const float* src = W2 + ((size_t)e * HID + ks * 32) * DIM + half * 512;
        unsigned short* lds = (unsigned short*)SM;   // [32][522]; conflict-free transpose stride
        const int kr = t >> 4, ch = t & 15;
        #pragma unroll
        for (int q = 0; q < 8; ++q) {
            float4 f4 = *(const float4*)(src + (size_t)kr * DIM + ch * 32 + q * 4);
            int c = ch * 32 + q * 4;
            lds[kr * 522 + c + 0] = f2bf(f4.x); lds[kr * 522 + c + 1] = f2bf(f4.y);
            lds[kr * 522 + c + 2] = f2bf(f4.z); lds[kr * 522 + c + 3] = f2bf(f4.w);
        }
        __syncthreads();
        uint4* dv = (uint4*)(W2F + (((size_t)(e * 64 + ks)) * 64 + half * 32) * 512);
        #pragma unroll
        for (int i = 0; i < 4; ++i) {
            int Q = t + 512 * i;
            int fl = Q >> 6, l = Q & 63;
            int cb = fl * 16 + (l & 15), rb = (l >> 4) * 8;
            unsigned short v[8];
            #pragma unroll
            for (int j = 0; j < 8; ++j) v[j] = lds[(rb + j) * 522 + cb];
            dv[Q] = *(const uint4*)v;
        }
        return;
    }

    // ---- gemm1 ----
    const int e  = bid & 7;
    const int q  = bid >> 3;       // 0..95
    const int mt = q % 6;          // 0..5
    const int nt = q / 6;          // 0..15

    int cnt = counts[e];
    int off = 0;
    #pragma unroll
    for (int j = 0; j < NEXP; ++j) if (j < e) off += counts[j];
    if (off + cnt > HROWS) cnt = HROWS - off;
    const int m0 = mt * 256;
    if (m0 >= cnt) return;

    const int lane = t & 63;
    const int wid  = t >> 6;     // 0..7
    const int wm   = wid >> 1;   // 0..3
    const int wn   = wid & 1;    // 0..1

    // A: wave w stages m-frags w and w+8; rows are CONTIGUOUS in xg (compact slots)
    const unsigned short* ag0 = xg + (size_t)(off + m0 + wid * 16 + (lane & 15)) * DIM + (lane >> 4) * 8;
    const unsigned short* ag1 = ag0 + (size_t)128 * DIM;

    // B: wave w stages col-frag nt*8+w
    const unsigned short* bg = W1F + ((size_t)(e * 32) * 128 + nt * 8 + wid) * 512 + lane * 8;

    f32x4 acc[4][4];
    #pragma unroll
    for (int m = 0; m < 4; ++m)
        #pragma unroll
        for (int n = 0; n < 4; ++n) acc[m][n] = (f32x4){0.f, 0.f, 0.f, 0.f};

#define STG1(P, KS) do { \
        gload16(ag0 + (KS) * 32, (P) + wid * 64); \
        gload16(ag1 + (KS) * 32, (P) + (wid + 8) * 64); \
        gload16(bg + (size_t)(KS) * 65536, (P) + 1024 + wid * 64); \
    } while (0)
#define CMP1(P) do { \
        const bf16x8* Af = (const bf16x8*)(P); \
        const bf16x8* Bf = (const bf16x8*)((P) + 1024); \
        bf16x8 af[4], bfr[4]; \
        _Pragma("unroll") for (int m = 0; m < 4; ++m) af[m] = Af[((wm * 4 + m) << 6) | lane]; \
        _Pragma("unroll") for (int n = 0; n < 4; ++n) bfr[n] = Bf[((wn * 4 + n) << 6) | lane]; \
        __builtin_amdgcn_s_setprio(1); \
        _Pragma("unroll") for (int m = 0; m < 4; ++m) \
            _Pragma("unroll") for (int n = 0; n < 4; ++n) \
                acc[m][n] = __builtin_amdgcn_mfma_f32_16x16x32_bf16(af[m], bfr[n], acc[m][n], 0, 0, 0); \
        __builtin_amdgcn_s_setprio(0); \
    } while (0)

    uint4 *P0 = SM, *P1 = SM + 1536, *P2 = SM + 3072;
    STG1(P0, 0);
    STG1(P1, 1);
    for (int T = 0; T < 30; ++T) {
        WAITK(3);                 // tile T landed (issued 2 iters ago); my ds_reads retired
        BAR();
        STG1(P2, T + 2);
        CMP1(P0);
        uint4* tmp = P0; P0 = P1; P1 = P2; P2 = tmp;
    }
    WAITK(3); BAR(); CMP1(P0);
    { uint4* tmp = P0; P0 = P1; P1 = P2; P2 = tmp; }
    WAITK(0); BAR(); CMP1(P0);
#undef STG1
#undef CMP1

    // ---- epilogue: bias + gelu -> XOR-swizzled LDS repack -> coalesced flush ----
    asm volatile("s_waitcnt lgkmcnt(0)" ::: "memory");
    BAR();                                    // SM free to reuse
    unsigned short* hb = (unsigned short*)SM; // [256][144] shorts = 72KB
    const int lg = lane >> 4;                 // bank-octet group
    #pragma unroll
    for (int n = 0; n < 4; ++n) {
        const int cl = (wn * 4 + n) * 16 + (lane & 15);
        const float bb = b1[e * HID + nt * 128 + cl];
        #pragma unroll
        for (int m = 0; m < 4; ++m) {
            const int il = (wm * 4 + m) * 16 + (lg << 2);
            const int scl = cl ^ (lg << 4);   // swizzle: group -> distinct 32B block
            #pragma unroll
            for (int r = 0; r < 4; ++r) {
                float v = acc[m][n][r] + bb;
                float g = 0.5f * v * (1.0f + erff(v * 0.70710678118654752f));
                hb[(il + r) * 144 + scl] = f2bf(g);
            }
        }
    }
    __syncthreads();
    #pragma unroll
    for (int s = 0; s < 8; ++s) {
        const int row = s * 32 + (t >> 4);
        if (m0 + row < cnt) {
            const int p = t & 15;
            const int gblk = ((p >> 1) ^ ((row >> 2) & 3));    // un-swizzle 32B block
            const int gc = gblk * 16 + (p & 1) * 8;
            uint4 v = *(const uint4*)(hb + row * 144 + p * 8);
            *(uint4*)(h + (size_t)(off + m0 + row) * HID + nt * 128 + gc) = v;
        }
    }
}

// ---------------- GEMM2: cbuf[slot] = wt * (h @ W2F + b2[e]) ----------------
// BM=128 BN=128 BK=32, 256 thr (4 waves 2Mx2N, 64x64/wave), 3-buf 48KB
// grid: id = ((mt*8 + nt) << 3) | e
__global__ __launch_bounds__(256, 4) void gemm2_store(
    const unsigned short* __restrict__ h, const unsigned short* __restrict__ W2F,
    const float* __restrict__ b2, const int* __restrict__ counts,
    const int* __restrict__ lists, const float* __restrict__ routing,
    float* __restrict__ cbuf)
{
    const int id = blockIdx.x;
    const int e  = id & 7;
    const int nt = (id >> 3) & 7;
    const int mt = id >> 6;          // 0..11

    int cnt = counts[e];
    int off = 0;
    #pragma unroll
    for (int j = 0; j < NEXP; ++j) if (j < e) off += counts[j];
    if (off + cnt > HROWS) cnt = HROWS - off;
    const int m0 = mt * 128;
    if (m0 >= cnt) return;

    __shared__ uint4 SM[3072];   // 3 x (A 512 + B 512) uint4 = 48KB

    const int t    = threadIdx.x;
    const int lane = t & 63;
    const int wid  = t >> 6;     // 0..3
    const int wm   = wid >> 1;   // 0..1
    const int wn   = wid & 1;    // 0..1

    // A: wave w stages m-frags w and w+4 (h rows compact per expert)
    const int r0 = off + m0 + wid * 16 + (lane & 15);
    const unsigned short* ag0 = h + (size_t)r0 * HID + (lane >> 4) * 8;
    const unsigned short* ag1 = ag0 + (size_t)64 * HID;

    // B: wave w stages col-frags nt*8+w and nt*8+w+4
    const unsigned short* bg0 = W2F + ((size_t)(e * 64) * 64 + nt * 8 + wid) * 512 + lane * 8;
    const unsigned short* bg1 = bg0 + 4 * 512;

    f32x4 acc[4][4];
    #pragma unroll
    for (int m = 0; m < 4; ++m)
        #pragma unroll
        for (int n = 0; n < 4; ++n) acc[m][n] = (f32x4){0.f, 0.f, 0.f, 0.f};

#define STG2(P, KS) do { \
        gload16(ag0 + (KS) * 32, (P) + wid * 64); \
        gload16(ag1 + (KS) * 32, (P) + (wid + 4) * 64); \
        gload16(bg0 + (size_t)(KS) * 32768, (P) + 512 + wid * 64); \
        gload16(bg1 + (size_t)(KS) * 32768, (P) + 512 + (wid + 4) * 64); \
    } while (0)
#define CMP2(P) do { \
        const bf16x8* Af = (const bf16x8*)(P); \
        const bf16x8* Bf = (const bf16x8*)((P) + 512); \
        bf16x8 af[4], bfr[4]; \
        _Pragma("unroll") for (int m = 0; m < 4; ++m) af[m] = Af[((wm * 4 + m) << 6) | lane]; \
        _Pragma("unroll") for (int n = 0; n < 4; ++n) bfr[n] = Bf[((wn * 4 + n) << 6) | lane]; \
        __builtin_amdgcn_s_setprio(1); \
        _Pragma("unroll") for (int m = 0; m < 4; ++m) \
            _Pragma("unroll") for (int n = 0; n < 4; ++n) \
                acc[m][n] = __builtin_amdgcn_mfma_f32_16x16x32_bf16(af[m], bfr[n], acc[m][n], 0, 0, 0); \
        __builtin_amdgcn_s_setprio(0); \
    } while (0)

    uint4 *P0 = SM, *P1 = SM + 1024, *P2 = SM + 2048;
    STG2(P0, 0);
    STG2(P1, 1);
    for (int T = 0; T < 62; ++T) {
        WAITK(4);
        BAR();
        STG2(P2, T + 2);
        CMP2(P0);
        uint4* tmp = P0; P0 = P1; P1 = P2; P2 = tmp;
    }
    WAITK(4); BAR(); CMP2(P0);
    { uint4* tmp = P0; P0 = P1; P1 = P2; P2 = tmp; }
    WAITK(0); BAR(); CMP2(P0);
#undef STG2
#undef CMP2

    const int n0 = nt * 128;
    int cols[4]; float bb[4];
    #pragma unroll
    for (int n = 0; n < 4; ++n) {
        cols[n] = n0 + (wn * 4 + n) * 16 + (lane & 15);
        bb[n] = b2[e * DIM + cols[n]];
    }
    #pragma unroll
    for (int m = 0; m < 4; ++m) {
        const int ib = m0 + (wm * 4 + m) * 16 + ((lane >> 4) << 2);
        #pragma unroll
        for (int r = 0; r < 4; ++r) {
            const int i = ib + r;
            if (i < cnt) {
                const int token = lists[e * NTOK + i];
                const float wt = routing[token * NEXP + e];
                float* dst = cbuf + (size_t)(off + i) * DIM;
                #pragma unroll
                for (int n = 0; n < 4; ++n)
                    dst[cols[n]] = wt * (acc[m][n][r] + bb[n]);
            }
        }
    }
}

// ---------------- combine: out[n] = sum over the token's slots ----------------
__global__ __launch_bounds__(256) void combine(
    const float* __restrict__ cbuf, const int* __restrict__ counts,
    const int* __restrict__ slotrec, const int* __restrict__ scnt,
    float* __restrict__ out)
{
    const int n = blockIdx.x;
    const int t = threadIdx.x;
    int offs[NEXP];
    int s = 0;
    #pragma unroll
    for (int e = 0; e < NEXP; ++e) { offs[e] = s; s += counts[e]; }
    int sc = scnt[n]; if (sc > 4) sc = 4;
    float4 acc = {0.f, 0.f, 0.f, 0.f};
    for (int j = 0; j < sc; ++j) {
        int rec = slotrec[n * 4 + j];
        int e = rec >> 20, i = rec & 0xFFFFF;
        float4 v = ((const float4*)(cbuf + (size_t)(offs[e] + i) * DIM))[t];
        acc.x += v.x; acc.y += v.y; acc.z += v.z; acc.w += v.w;
    }
    ((float4*)(out + (size_t)n * DIM))[t] = acc;
}

extern "C" void kernel_launch(void* const* d_in, const int* in_sizes, int n_in,
                              void* d_out, int out_size, void* d_ws, size_t ws_size,
                              hipStream_t stream) {
    const float* x       = (const float*)d_in[0];
    const float* routing = (const float*)d_in[1];
    const float* W1      = (const float*)d_in[2];
    const float* b1      = (const float*)d_in[3];
    const float* W2      = (const float*)d_in[4];
    const float* b2      = (const float*)d_in[5];
    float* out = (float*)d_out;

    char* ws = (char*)d_ws;
    int* counts          = (int*)ws;                            // 256 B
    int* lists           = (int*)(ws + 0x400);                  // 128 KB
    int* slotrec         = (int*)(ws + 0x20400);                // 64 KB
    int* scnt            = (int*)(ws + 0x30400);                // 16 KB
    unsigned short* xg   = (unsigned short*)(ws + 0x40000);     // 17.3 MB (compact gathered x)
    float*          cbuf = (float*)(ws + 0x40000);              // 34.6 MB, overlays xg+W1F (dead after gemm1)
    unsigned short* W1F  = (unsigned short*)(ws + 0x1100000);   // 32 MB
    unsigned short* W2F  = (unsigned short*)(ws + 0x3100000);   // 32 MB
    unsigned short* h    = (unsigned short*)(ws + 0x5100000);   // 34.6 MB -> ends ~0x7200000

    hipMemsetAsync(counts, 0, 256, stream);
    prep<<<2064, 256, 0, stream>>>(x, routing, W1, W1F,
                                   counts, lists, slotrec, scnt);
    gather_x<<<528, 256, 0, stream>>>(x, counts, lists, xg);
    gemm1_gelu<<<1792, 512, 0, stream>>>(xg, W1F, b1, counts, h, W2, W2F);
    gemm2_store<<<768, 256, 0, stream>>>(h, W2F, b2, counts, lists, routing, cbuf);
    combine<<<NTOK, 256, 0, stream>>>(cbuf, counts, slotrec, scnt, out);
}

// Round 8
// 183.651 us; speedup vs baseline: 1.1089x; 1.1042x over previous
//
#include <hip/hip_runtime.h>
#include <hip/hip_bf16.h>

#define NTOK 4096
#define DIM  1024
#define NEXP 8
#define HID  2048
#define HROWS 8448   // capacity rows for h (8192 expected + slack)

typedef __attribute__((ext_vector_type(8))) __bf16 bf16x8;
typedef __attribute__((ext_vector_type(4))) float  f32x4;
typedef __attribute__((address_space(1))) const unsigned char gconst_u8;
typedef __attribute__((address_space(3))) unsigned char lds_u8;

__device__ __forceinline__ unsigned short f2bf(float f) {
    unsigned u = __float_as_uint(f);
    u += 0x7fffu + ((u >> 16) & 1u);   // RNE
    return (unsigned short)(u >> 16);
}

__device__ __forceinline__ void gload16(const void* g, void* l) {
    __builtin_amdgcn_global_load_lds((gconst_u8*)g, (lds_u8*)l, 16, 0, 0);
}

#define WAITK(N) asm volatile("s_waitcnt vmcnt(" #N ") lgkmcnt(0)" ::: "memory")
#define BAR() do { __builtin_amdgcn_s_barrier(); __builtin_amdgcn_sched_barrier(0); } while (0)

// ---------------- prep: W1 convert + x convert + build_lists ----------------
// bid 0..2047    : W1 -> W1F fragment-tiled bf16
// bid 2048..4095 : x -> xbf
// bid 4096..4111 : build per-expert token lists
// W1F elem((e*32+ks)*128 + f, l, j) = W1[e][k = ks*32+(l>>4)*8+j][c = f*16+(l&15)]
__global__ __launch_bounds__(256) void prep(
    const float* __restrict__ x, const float* __restrict__ routing,
    const float* __restrict__ W1,
    unsigned short* __restrict__ xbf, unsigned short* __restrict__ W1F,
    int* __restrict__ counts, int* __restrict__ lists,
    int* __restrict__ slotrec, int* __restrict__ scnt)
{
    const int bid = blockIdx.x;
    const int t = threadIdx.x;
    if (bid >= 4096) {            // build_lists
        int n = (bid - 4096) * 256 + t;
        if (n >= NTOK) return;
        int sc = 0;
        #pragma unroll
        for (int e = 0; e < NEXP; ++e) {
            if (routing[n * NEXP + e] > 0.0f) {
                int i = atomicAdd(&counts[e], 1);
                if (i < NTOK) {
                    lists[e * NTOK + i] = n;
                    if (sc < 4) slotrec[n * 4 + sc] = (e << 20) | i;
                    ++sc;
                }
            }
        }
        scnt[n] = sc;
        return;
    }
    if (bid >= 2048) {            // convert x
        int i = ((bid - 2048) * 256 + t) * 8;
        float4 a = *(const float4*)(x + i);
        float4 b = *(const float4*)(x + i + 4);
        unsigned short v[8];
        v[0] = f2bf(a.x); v[1] = f2bf(a.y); v[2] = f2bf(a.z); v[3] = f2bf(a.w);
        v[4] = f2bf(b.x); v[5] = f2bf(b.y); v[6] = f2bf(b.z); v[7] = f2bf(b.w);
        *(uint4*)(xbf + i) = *(const uint4*)v;
        return;
    }
    // W1: e(8) x ks(32) x fblk(8), 256 cols x 32 k per block
    int e = bid >> 8, ks = (bid >> 3) & 31, fblk = bid & 7;
    const float* src = W1 + ((size_t)e * DIM + ks * 32) * HID + fblk * 256;
    unsigned short* dst = W1F + (((size_t)(e * 32 + ks) * 128) + fblk * 16) * 512;
    __shared__ unsigned short lds[32][264];
    const int kr = t >> 3, ch = t & 7;
    #pragma unroll
    for (int q = 0; q < 8; ++q) {
        float4 f4 = *(const float4*)(src + (size_t)kr * HID + ch * 32 + q * 4);
        int c = ch * 32 + q * 4;
        ushort4 w;
        w.x = f2bf(f4.x); w.y = f2bf(f4.y); w.z = f2bf(f4.z); w.w = f2bf(f4.w);
        *(ushort4*)&lds[kr][c] = w;
    }
    __syncthreads();
    uint4* dv = (uint4*)dst;
    #pragma unroll
    for (int i = 0; i < 4; ++i) {
        int Q = t + 256 * i;
        int fl = Q >> 6, l = Q & 63;
        int cb = fl * 16 + (l & 15), rb = (l >> 4) * 8;
        unsigned short v[8];
        #pragma unroll
        for (int j = 0; j < 8; ++j) v[j] = lds[rb + j][cb];
        dv[Q] = *(const uint4*)v;
    }
}

// ---------------- GEMM1 (+piggybacked W2 convert): ----------------
// gemm1: BM=256 BN=128 BK=32, 512 thr (8 waves 4Mx2N, 64x64/wave)
//   3-buffer depth-2 prefetch, 1 barrier/step, vmcnt(3)
//   grid ids 0..767: id = ((nt*6 + mt) << 3) | e
// bids 768..1791: W2 -> W2F fragment-tiled convert (1024 units)
// W2F elem((e*64+ks)*64 + f, l, j) = W2[e][k=ks*32+(l>>4)*8+j][c=f*16+(l&15)]
__global__ __launch_bounds__(512, 4) void gemm1_gelu(
    const unsigned short* __restrict__ xbf, const unsigned short* __restrict__ W1F,
    const float* __restrict__ b1, const int* __restrict__ counts,
    const int* __restrict__ lists, unsigned short* __restrict__ h,
    const float* __restrict__ W2, unsigned short* __restrict__ W2F)
{
    __shared__ uint4 SM[4608];   // 3 x (A 1024 + B 512) uint4 = 72KB
    const int bid = blockIdx.x;
    const int t = threadIdx.x;

    if (bid >= 768) {            // ---- W2 -> W2F convert (512 thr) ----
        const int unit = bid - 768;
        const int e = unit & 7, ks = (unit >> 3) & 63, half = unit >> 9;
        const float* src = W2 + ((size_t)e * HID + ks * 32) * DIM + half * 512;
        unsigned short* lds = (unsigned short*)SM;   // [32][520]
        const int kr = t >> 4, ch = t & 15;
        #pragma unroll
        for (int q = 0; q < 8; ++q) {
            float4 f4 = *(const float4*)(src + (size_t)kr * DIM + ch * 32 + q * 4);
            int c = ch * 32 + q * 4;
            ushort4 w;
            w.x = f2bf(f4.x); w.y = f2bf(f4.y); w.z = f2bf(f4.z); w.w = f2bf(f4.w);
            *(ushort4*)&lds[kr * 520 + c] = w;
        }
        __syncthreads();
        uint4* dv = (uint4*)(W2F + (((size_t)(e * 64 + ks)) * 64 + half * 32) * 512);
        #pragma unroll
        for (int i = 0; i < 4; ++i) {
            int Q = t + 512 * i;
            int fl = Q >> 6, l = Q & 63;
            int cb = fl * 16 + (l & 15), rb = (l >> 4) * 8;
            unsigned short v[8];
            #pragma unroll
            for (int j = 0; j < 8; ++j) v[j] = lds[(rb + j) * 520 + cb];
            dv[Q] = *(const uint4*)v;
        }
        return;
    }

    // ---- gemm1 ----
    const int e  = bid & 7;
    const int q  = bid >> 3;       // 0..95
    const int mt = q % 6;          // 0..5
    const int nt = q / 6;          // 0..15

    int cnt = counts[e];
    int off = 0;
    #pragma unroll
    for (int j = 0; j < NEXP; ++j) if (j < e) off += counts[j];
    if (off + cnt > HROWS) cnt = HROWS - off;
    const int m0 = mt * 256;
    if (m0 >= cnt) return;

    const int lane = t & 63;
    const int wid  = t >> 6;     // 0..7
    const int wm   = wid >> 1;   // 0..3
    const int wn   = wid & 1;    // 0..1

    // A gather: wave w stages m-frags w and w+8 (rows f*16+(lane&15))
    const int gi0 = m0 + wid * 16 + (lane & 15);
    const int gi1 = gi0 + 128;
    const int tok0 = lists[e * NTOK + ((gi0 < cnt) ? gi0 : 0)];
    const int tok1 = lists[e * NTOK + ((gi1 < cnt) ? gi1 : 0)];
    const unsigned short* ag0 = xbf + (size_t)tok0 * DIM + (lane >> 4) * 8;
    const unsigned short* ag1 = xbf + (size_t)tok1 * DIM + (lane >> 4) * 8;

    // B: wave w stages col-frag nt*8+w
    const unsigned short* bg = W1F + ((size_t)(e * 32) * 128 + nt * 8 + wid) * 512 + lane * 8;

    f32x4 acc[4][4];
    #pragma unroll
    for (int m = 0; m < 4; ++m)
        #pragma unroll
        for (int n = 0; n < 4; ++n) acc[m][n] = (f32x4){0.f, 0.f, 0.f, 0.f};

#define STG1(P, KS) do { \
        gload16(ag0 + (KS) * 32, (P) + wid * 64); \
        gload16(ag1 + (KS) * 32, (P) + (wid + 8) * 64); \
        gload16(bg + (size_t)(KS) * 65536, (P) + 1024 + wid * 64); \
    } while (0)
#define CMP1(P) do { \
        const bf16x8* Af = (const bf16x8*)(P); \
        const bf16x8* Bf = (const bf16x8*)((P) + 1024); \
        bf16x8 af[4], bfr[4]; \
        _Pragma("unroll") for (int m = 0; m < 4; ++m) af[m] = Af[((wm * 4 + m) << 6) | lane]; \
        _Pragma("unroll") for (int n = 0; n < 4; ++n) bfr[n] = Bf[((wn * 4 + n) << 6) | lane]; \
        __builtin_amdgcn_s_setprio(1); \
        _Pragma("unroll") for (int m = 0; m < 4; ++m) \
            _Pragma("unroll") for (int n = 0; n < 4; ++n) \
                acc[m][n] = __builtin_amdgcn_mfma_f32_16x16x32_bf16(af[m], bfr[n], acc[m][n], 0, 0, 0); \
        __builtin_amdgcn_s_setprio(0); \
    } while (0)

    uint4 *P0 = SM, *P1 = SM + 1536, *P2 = SM + 3072;
    STG1(P0, 0);
    STG1(P1, 1);
    for (int T = 0; T < 30; ++T) {
        WAITK(3);                 // tile T landed (issued 2 iters ago); my ds_reads retired
        BAR();
        STG1(P2, T + 2);
        CMP1(P0);
        uint4* tmp = P0; P0 = P1; P1 = P2; P2 = tmp;
    }
    WAITK(3); BAR(); CMP1(P0);
    { uint4* tmp = P0; P0 = P1; P1 = P2; P2 = tmp; }
    WAITK(0); BAR(); CMP1(P0);
#undef STG1
#undef CMP1

    // ---- epilogue: bias + gelu -> XOR-swizzled LDS repack -> coalesced flush ----
    asm volatile("s_waitcnt lgkmcnt(0)" ::: "memory");
    BAR();                                    // SM free to reuse
    unsigned short* hb = (unsigned short*)SM; // [256][144] shorts = 72KB
    const int lg = lane >> 4;                 // bank-octet group
    #pragma unroll
    for (int n = 0; n < 4; ++n) {
        const int cl = (wn * 4 + n) * 16 + (lane & 15);
        const float bb = b1[e * HID + nt * 128 + cl];
        #pragma unroll
        for (int m = 0; m < 4; ++m) {
            const int il = (wm * 4 + m) * 16 + (lg << 2);
            const int scl = cl ^ (lg << 4);   // swizzle: group -> distinct 32B block
            #pragma unroll
            for (int r = 0; r < 4; ++r) {
                float v = acc[m][n][r] + bb;
                float g = 0.5f * v * (1.0f + erff(v * 0.70710678118654752f));
                hb[(il + r) * 144 + scl] = f2bf(g);
            }
        }
    }
    __syncthreads();
    #pragma unroll
    for (int s = 0; s < 8; ++s) {
        const int row = s * 32 + (t >> 4);
        if (m0 + row < cnt) {
            const int p = t & 15;
            const int gblk = ((p >> 1) ^ ((row >> 2) & 3));    // un-swizzle 32B block
            const int gc = gblk * 16 + (p & 1) * 8;
            uint4 v = *(const uint4*)(hb + row * 144 + p * 8);
            *(uint4*)(h + (size_t)(off + m0 + row) * HID + nt * 128 + gc) = v;
        }
    }
}

// ---------------- GEMM2: cbuf[slot] = wt * (h @ W2F + b2[e]) ----------------
// BM=128 BN=128 BK=32, 256 thr (4 waves 2Mx2N, 64x64/wave), 3-buf 48KB
// grid: id = ((mt*8 + nt) << 3) | e
__global__ __launch_bounds__(256, 4) void gemm2_store(
    const unsigned short* __restrict__ h, const unsigned short* __restrict__ W2F,
    const float* __restrict__ b2, const int* __restrict__ counts,
    const int* __restrict__ lists, const float* __restrict__ routing,
    float* __restrict__ cbuf)
{
    const int id = blockIdx.x;
    const int e  = id & 7;
    const int nt = (id >> 3) & 7;
    const int mt = id >> 6;          // 0..11

    int cnt = counts[e];
    int off = 0;
    #pragma unroll
    for (int j = 0; j < NEXP; ++j) if (j < e) off += counts[j];
    if (off + cnt > HROWS) cnt = HROWS - off;
    const int m0 = mt * 128;
    if (m0 >= cnt) return;

    __shared__ uint4 SM[3072];   // 3 x (A 512 + B 512) uint4 = 48KB

    const int t    = threadIdx.x;
    const int lane = t & 63;
    const int wid  = t >> 6;     // 0..3
    const int wm   = wid >> 1;   // 0..1
    const int wn   = wid & 1;    // 0..1

    // A: wave w stages m-frags w and w+4 (h rows compact per expert)
    const int r0 = off + m0 + wid * 16 + (lane & 15);
    const unsigned short* ag0 = h + (size_t)r0 * HID + (lane >> 4) * 8;
    const unsigned short* ag1 = ag0 + (size_t)64 * HID;

    // B: wave w stages col-frags nt*8+w and nt*8+w+4
    const unsigned short* bg0 = W2F + ((size_t)(e * 64) * 64 + nt * 8 + wid) * 512 + lane * 8;
    const unsigned short* bg1 = bg0 + 4 * 512;

    f32x4 acc[4][4];
    #pragma unroll
    for (int m = 0; m < 4; ++m)
        #pragma unroll
        for (int n = 0; n < 4; ++n) acc[m][n] = (f32x4){0.f, 0.f, 0.f, 0.f};

#define STG2(P, KS) do { \
        gload16(ag0 + (KS) * 32, (P) + wid * 64); \
        gload16(ag1 + (KS) * 32, (P) + (wid + 4) * 64); \
        gload16(bg0 + (size_t)(KS) * 32768, (P) + 512 + wid * 64); \
        gload16(bg1 + (size_t)(KS) * 32768, (P) + 512 + (wid + 4) * 64); \
    } while (0)
#define CMP2(P) do { \
        const bf16x8* Af = (const bf16x8*)(P); \
        const bf16x8* Bf = (const bf16x8*)((P) + 512); \
        bf16x8 af[4], bfr[4]; \
        _Pragma("unroll") for (int m = 0; m < 4; ++m) af[m] = Af[((wm * 4 + m) << 6) | lane]; \
        _Pragma("unroll") for (int n = 0; n < 4; ++n) bfr[n] = Bf[((wn * 4 + n) << 6) | lane]; \
        __builtin_amdgcn_s_setprio(1); \
        _Pragma("unroll") for (int m = 0; m < 4; ++m) \
            _Pragma("unroll") for (int n = 0; n < 4; ++n) \
                acc[m][n] = __builtin_amdgcn_mfma_f32_16x16x32_bf16(af[m], bfr[n], acc[m][n], 0, 0, 0); \
        __builtin_amdgcn_s_setprio(0); \
    } while (0)

    uint4 *P0 = SM, *P1 = SM + 1024, *P2 = SM + 2048;
    STG2(P0, 0);
    STG2(P1, 1);
    for (int T = 0; T < 62; ++T) {
        WAITK(4);
        BAR();
        STG2(P2, T + 2);
        CMP2(P0);
        uint4* tmp = P0; P0 = P1; P1 = P2; P2 = tmp;
    }
    WAITK(4); BAR(); CMP2(P0);
    { uint4* tmp = P0; P0 = P1; P1 = P2; P2 = tmp; }
    WAITK(0); BAR(); CMP2(P0);
#undef STG2
#undef CMP2

    const int n0 = nt * 128;
    int cols[4]; float bb[4];
    #pragma unroll
    for (int n = 0; n < 4; ++n) {
        cols[n] = n0 + (wn * 4 + n) * 16 + (lane & 15);
        bb[n] = b2[e * DIM + cols[n]];
    }
    #pragma unroll
    for (int m = 0; m < 4; ++m) {
        const int ib = m0 + (wm * 4 + m) * 16 + ((lane >> 4) << 2);
        #pragma unroll
        for (int r = 0; r < 4; ++r) {
            const int i = ib + r;
            if (i < cnt) {
                const int token = lists[e * NTOK + i];
                const float wt = routing[token * NEXP + e];
                float* dst = cbuf + (size_t)(off + i) * DIM;
                #pragma unroll
                for (int n = 0; n < 4; ++n)
                    dst[cols[n]] = wt * (acc[m][n][r] + bb[n]);
            }
        }
    }
}

// ---------------- combine: out[n] = sum over the token's slots ----------------
__global__ __launch_bounds__(256) void combine(
    const float* __restrict__ cbuf, const int* __restrict__ counts,
    const int* __restrict__ slotrec, const int* __restrict__ scnt,
    float* __restrict__ out)
{
    const int n = blockIdx.x;
    const int t = threadIdx.x;
    int offs[NEXP];
    int s = 0;
    #pragma unroll
    for (int e = 0; e < NEXP; ++e) { offs[e] = s; s += counts[e]; }
    int sc = scnt[n]; if (sc > 4) sc = 4;
    float4 acc = {0.f, 0.f, 0.f, 0.f};
    for (int j = 0; j < sc; ++j) {
        int rec = slotrec[n * 4 + j];
        int e = rec >> 20, i = rec & 0xFFFFF;
        float4 v = ((const float4*)(cbuf + (size_t)(offs[e] + i) * DIM))[t];
        acc.x += v.x; acc.y += v.y; acc.z += v.z; acc.w += v.w;
    }
    ((float4*)(out + (size_t)n * DIM))[t] = acc;
}

extern "C" void kernel_launch(void* const* d_in, const int* in_sizes, int n_in,
                              void* d_out, int out_size, void* d_ws, size_t ws_size,
                              hipStream_t stream) {
    const float* x       = (const float*)d_in[0];
    const float* routing = (const float*)d_in[1];
    const float* W1      = (const float*)d_in[2];
    const float* b1      = (const float*)d_in[3];
    const float* W2      = (const float*)d_in[4];
    const float* b2      = (const float*)d_in[5];
    float* out = (float*)d_out;

    char* ws = (char*)d_ws;
    int* counts          = (int*)ws;                            // 256 B
    int* lists           = (int*)(ws + 0x400);                  // 128 KB
    int* slotrec         = (int*)(ws + 0x20400);                // 64 KB
    int* scnt            = (int*)(ws + 0x30400);                // 16 KB
    unsigned short* xbf  = (unsigned short*)(ws + 0x40000);     // 8 MB
    float*          cbuf = (float*)(ws + 0x40000);              // overlays xbf+W1F (dead after gemm1)
    unsigned short* W1F  = (unsigned short*)(ws + 0x840000);    // 32 MB
    unsigned short* W2F  = (unsigned short*)(ws + 0x2840000);   // 32 MB
    unsigned short* h    = (unsigned short*)(ws + 0x4840000);   // 35 MB

    hipMemsetAsync(counts, 0, 256, stream);
    prep<<<4112, 256, 0, stream>>>(x, routing, W1, xbf, W1F,
                                   counts, lists, slotrec, scnt);
    gemm1_gelu<<<1792, 512, 0, stream>>>(xbf, W1F, b1, counts, lists, h, W2, W2F);
    gemm2_store<<<768, 256, 0, stream>>>(h, W2F, b2, counts, lists, routing, cbuf);
    combine<<<NTOK, 256, 0, stream>>>(cbuf, counts, slotrec, scnt, out);
}